// Round 11
// baseline (306.489 us; speedup 1.0000x reference)
//
#include <hip/hip_runtime.h>

#define NROWS 8192      // 128 sequences * 64 positions
#define NZX   2304      // z (1024) + xBC (1280) columns from in-proj
#define BCS   136       // Bs/Cs LDS row stride (elements, padded)
#define XMS   72        // XsT/Ms LDS row stride (elements, padded)

// prep kernel block ranges
#define PB0 2048            // fold_w
#define PB1 (PB0 + 2304)    // cvt in_w (both dirs)
#define PB2 (PB1 + 256)     // cvtT out_w (both dirs)
#define PB3 (PB2 + 512)     // dt_cs (both dirs, 8 heads/block) + xbf write

typedef __attribute__((ext_vector_type(8))) short bf16x8;
typedef __attribute__((ext_vector_type(4))) float f32x4;

__device__ __forceinline__ float bf2f(unsigned short u) {
    union { unsigned int i; float f; } v; v.i = ((unsigned int)u) << 16; return v.f;
}
// fast bf16 round (half-up): 2 VALU ops
__device__ __forceinline__ unsigned short f2bf(float f) {
    union { float f; unsigned int i; } v; v.f = f;
    return (unsigned short)((v.i + 0x8000u) >> 16);
}

// async global->LDS, 16B per lane; lane's LDS slot must be wave-base + lane*16.
__device__ __forceinline__ void async_lds16(const unsigned short* g, unsigned short* l) {
    __builtin_amdgcn_global_load_lds(
        (const __attribute__((address_space(1))) unsigned int*)g,
        (__attribute__((address_space(3))) unsigned int*)l, 16, 0, 0);
}

// ---------------------------------------------------------------------------
// PREP: weight conversions + dt/cumsum path (+ xbf write), block-range based.
// ---------------------------------------------------------------------------
__global__ __launch_bounds__(256) void prep_kernel(
    const float* __restrict__ x, const float* __restrict__ fcw,
    const float* __restrict__ iw0, const float* __restrict__ iw1,
    const float* __restrict__ ow0, const float* __restrict__ ow1,
    const float* __restrict__ db0, const float* __restrict__ db1,
    const float* __restrict__ al0, const float* __restrict__ al1,
    unsigned short* __restrict__ xbf, unsigned short* __restrict__ wf,
    unsigned short* __restrict__ wbA, unsigned short* __restrict__ wbOT0,
    unsigned short* __restrict__ wbOT1, float* __restrict__ dtbb,
    float* __restrict__ csbb)
{
    __shared__ char sm[37888] __attribute__((aligned(16)));
    const int blk = blockIdx.x, tid = threadIdx.x;
    if (blk < PB0) {
        int idx = blk * 256 + tid;
        int o = idx >> 10, c = idx & 1023;
        int half = c >> 9, cc = c & 511;
        float v = fcw[(size_t)o * 2048 + half * 1024 + cc] +
                  fcw[(size_t)o * 2048 + half * 1024 + 512 + cc];
        wf[idx] = f2bf(v);
    } else if (blk < PB1) {
        int local = blk - PB0;
        int dir = local / 1152;
        int i = (local % 1152) * 256 + tid;
        const float* s = dir ? iw1 : iw0;
        float4 v = *(const float4*)(s + (size_t)i * 4);
        ushort4 o;
        o.x = f2bf(v.x); o.y = f2bf(v.y); o.z = f2bf(v.z); o.w = f2bf(v.w);
        *(ushort4*)(wbA + (size_t)dir * (2304 * 512) + (size_t)i * 4) = o;
    } else if (blk < PB2) {
        float (*T)[65] = (float(*)[65])sm;
        int local = blk - PB1;
        int z = local >> 7, rem = local & 127;
        const float* s = z ? ow1 : ow0;
        unsigned short* d = z ? wbOT1 : wbOT0;
        const int bo = (rem >> 4) * 64, bc = (rem & 15) * 64;
#pragma unroll
        for (int i = 0; i < 16; ++i) {
            int slot = tid + i * 256;
            int r = slot >> 6, c = slot & 63;
            T[r][c] = s[(size_t)(bo + r) * 1024 + bc + c];
        }
        __syncthreads();
#pragma unroll
        for (int i = 0; i < 16; ++i) {
            int slot = tid + i * 256;
            int cr = slot >> 6, oc = slot & 63;
            d[(size_t)(bc + cr) * 512 + bo + oc] = f2bf(T[oc][cr]);
        }
    } else {
        // dt path fp32, both dirs; 256 blocks/dir; block = (seq, 8-head half).
        // dir0/half0 blocks also emit xbf (bf16 x) from the staged tiles.
        float (*wsm)[512] = (float(*)[512])sm;                       // 16 KB
        float (*xs)[68]   = (float(*)[68])(sm + 16384);              // 17.4 KB
        float (*dta)[64]  = (float(*)[64])(sm + 16384 + 17408);      // 2 KB
        float (*dtt)[64]  = (float(*)[64])(sm + 16384 + 17408 + 2048);
        int local = blk - PB2;
        const int dir = local >> 8, bxl = local & 255;
        const float* in_w = dir ? iw1 : iw0;
        const float* dt_bias = dir ? db1 : db0;
        const float* A_log = dir ? al1 : al0;
        float* dtb = dtbb + (size_t)dir * 131072;
        float* csb = csbb + (size_t)dir * 131072;
        const int seq = bxl >> 1, hq = bxl & 1;
        const bool emit_x = (dir == 0) && (hq == 0);
#pragma unroll
        for (int i = 0; i < 4; ++i) {
            int slot = tid + i * 256;
            int h = slot >> 7, c = (slot & 127) * 4;
            *(float4*)&wsm[h][c] = *(const float4*)(in_w + (size_t)(2304 + hq * 8 + h) * 512 + c);
        }
        const int t = tid & 63, hg = tid >> 6;   // 2 heads per thread
        float acc[2] = {0.f, 0.f};
        for (int c0 = 0; c0 < 512; c0 += 64) {
            __syncthreads();
#pragma unroll
            for (int i = 0; i < 4; ++i) {
                int slot = tid + i * 256;
                int r = slot >> 4, cc = (slot & 15) * 4;
                size_t row = (dir == 0) ? (size_t)seq * 64 + r
                                        : (size_t)(seq >> 6) * 4096 + (size_t)r * 64 + (seq & 63);
                *(float4*)&xs[r][cc] = *(const float4*)(x + row * 512 + c0 + cc);
            }
            __syncthreads();
            if (emit_x) {
#pragma unroll
                for (int i = 0; i < 2; ++i) {
                    int slot = tid + i * 256;        // 512 chunks of 8
                    int r = slot >> 3, cc8 = (slot & 7) * 8;
                    unsigned short o8[8] __attribute__((aligned(16)));
#pragma unroll
                    for (int j = 0; j < 8; ++j) o8[j] = f2bf(xs[r][cc8 + j]);
                    *(uint4*)(xbf + (size_t)(seq * 64 + r) * 512 + c0 + cc8) =
                        *(const uint4*)o8;
                }
            }
#pragma unroll
            for (int cc = 0; cc < 64; cc += 4) {
                float4 u4 = *(const float4*)&xs[t][cc];
                const float* w0 = &wsm[hg * 2][c0 + cc];
                const float* w1 = &wsm[hg * 2 + 1][c0 + cc];
                acc[0] += u4.x * w0[0] + u4.y * w0[1] + u4.z * w0[2] + u4.w * w0[3];
                acc[1] += u4.x * w1[0] + u4.y * w1[1] + u4.z * w1[2] + u4.w * w1[3];
            }
        }
#pragma unroll
        for (int hh = 0; hh < 2; ++hh) {
            int hl = hg * 2 + hh;
            int h = hq * 8 + hl;
            float v = acc[hh] + dt_bias[h];
            float dtv = (v > 20.f) ? v : log1pf(__expf(v));
            dtt[hl][t] = dtv;
            dta[hl][t] = dtv * -__expf(A_log[h]);
        }
        __syncthreads();
        if (tid < 8) {
            float run = 0.f;
            int ob = (seq * 16 + hq * 8 + tid) * 64;
            for (int tt = 0; tt < 64; ++tt) {
                run += dta[tid][tt];
                dtb[ob + tt] = dtt[tid][tt];
                csb[ob + tt] = run;
            }
        }
    }
}

// ---------------------------------------------------------------------------
// GEMM phase (one launch, BK=64): bx<64 -> in-proj (M=8192,N=2304,K=512,
// perm on z=1); bx>=64 -> wcomb halves (M=512,N=1024,K=512). bf16 out.
// ---------------------------------------------------------------------------
__global__ __launch_bounds__(256) void gemm_phase(
    const unsigned short* __restrict__ xbf, const unsigned short* __restrict__ wbA,
    unsigned short* __restrict__ zx, const unsigned short* __restrict__ wf,
    const unsigned short* __restrict__ wbOT0, const unsigned short* __restrict__ wbOT1,
    unsigned short* __restrict__ wcomb)
{
    __shared__ unsigned short SMEM[16384];   // As = [0,8192), Bs = [8192,16384)
    unsigned short* As = SMEM;
    unsigned short* Bs = SMEM + 8192;
    const int bx = blockIdx.x, by = blockIdx.y, z = blockIdx.z;
    const unsigned short *A, *B;
    unsigned short* C;
    int lda, ldb, ldc, perm, mB, nB;
    if (bx < 64) {
        A = xbf; lda = 512; perm = z;
        B = wbA + (size_t)z * (2304 * 512); ldb = 512;
        C = zx + (size_t)z * NROWS * NZX; ldc = NZX;
        mB = bx * 128; nB = by * 128;
    } else {
        if (by >= 8) return;
        A = z ? wf : wf + 512; lda = 1024; perm = 0;
        B = z ? wbOT1 : wbOT0; ldb = 512;
        C = z ? wcomb : wcomb + 1024; ldc = 2048;
        mB = (bx - 64) * 128; nB = by * 128;
    }
    const int tid = threadIdx.x, wave = tid >> 6, lane = tid & 63;
    const int wm = (wave >> 1) * 64, wn = (wave & 1) * 64;
    const int lr = lane & 15, lq = lane >> 4;
    const unsigned short* AgP[4];
    const unsigned short* BgP[4];
    unsigned short* lA[4];
    unsigned short* lB[4];
#pragma unroll
    for (int i = 0; i < 4; ++i) {
        int s = tid + i * 256;              // 1024 slots each
        int r = s >> 3, p = s & 7;
        int q = p ^ (r & 7);
        int ar = mB + r;
        if (perm) ar = (ar & ~4095) | ((ar & 63) << 6) | ((ar >> 6) & 63);
        AgP[i] = A + (size_t)ar * lda + q * 8;
        BgP[i] = B + (size_t)(nB + r) * ldb + q * 8;
        lA[i] = As + s * 8;
        lB[i] = Bs + s * 8;
    }
    const int aswz = lr & 7;
    int arb[4], brb[4];
#pragma unroll
    for (int i = 0; i < 4; ++i) {
        arb[i] = (wm + i * 16 + lr) * 64;
        brb[i] = (wn + i * 16 + lr) * 64;
    }
    f32x4 zero4 = {0.f,0.f,0.f,0.f};
    f32x4 acc[4][4] = {{zero4,zero4,zero4,zero4},{zero4,zero4,zero4,zero4},
                       {zero4,zero4,zero4,zero4},{zero4,zero4,zero4,zero4}};
    for (int k0 = 0; k0 < 512; k0 += 64) {
#pragma unroll
        for (int i = 0; i < 4; ++i) async_lds16(AgP[i] + k0, lA[i]);
#pragma unroll
        for (int i = 0; i < 4; ++i) async_lds16(BgP[i] + k0, lB[i]);
        __syncthreads();
#pragma unroll
        for (int kh = 0; kh < 2; ++kh) {
            const int ksw = ((kh * 4 + lq) ^ aswz) * 8;
            bf16x8 a[4], b[4];
#pragma unroll
            for (int i = 0; i < 4; ++i) a[i] = *(const bf16x8*)(As + arb[i] + ksw);
#pragma unroll
            for (int i = 0; i < 4; ++i) b[i] = *(const bf16x8*)(Bs + brb[i] + ksw);
#pragma unroll
            for (int mi = 0; mi < 4; ++mi)
#pragma unroll
                for (int ni = 0; ni < 4; ++ni)
                    acc[mi][ni] = __builtin_amdgcn_mfma_f32_16x16x32_bf16(
                        a[mi], b[ni], acc[mi][ni], 0, 0, 0);
        }
        __syncthreads();
    }
    // ---- epilogue: wave-private 16x64 LDS tile, granule-rotated, 16B stores
    unsigned short* WR = SMEM + wave * 1024;
#pragma unroll
    for (int mi = 0; mi < 4; ++mi) {
#pragma unroll
        for (int ni = 0; ni < 4; ++ni) {
#pragma unroll
            for (int r = 0; r < 4; ++r) {
                int r16 = lq * 4 + r;
                int cn = ni * 16 + lr;
                int gp = ((cn >> 3) + (r16 >> 1)) & 7;
                WR[r16 * 64 + gp * 8 + (cn & 7)] = f2bf(acc[mi][ni][r]);
            }
        }
#pragma unroll
        for (int j = 0; j < 2; ++j) {
            int r16 = j * 8 + (lane >> 3);
            int gr = lane & 7;
            int gp = (gr + (r16 >> 1)) & 7;
            uint4 v = *(const uint4*)(WR + r16 * 64 + gp * 8);
            int row = mB + wm + mi * 16 + r16;
            *(uint4*)(C + (size_t)row * ldc + nB + wn + gr * 8) = v;
        }
    }
}

// ---------------------------------------------------------------------------
// Final GEMM, 128x64 tiles, BK=64 (512 blocks): out[r,o] =
//   sum_{k<1024} yv[perm(r),k]*Wc[o,k] + sum_{k>=1024} yh[r,k-1024]*Wc[o,k]
//   + bias[o]; fp32 out. M=8192, N=512, K=2048, Wc ld 2048.
// ---------------------------------------------------------------------------
__global__ __launch_bounds__(256) void gemm_final2048(
    const unsigned short* __restrict__ YV, const unsigned short* __restrict__ YH,
    const unsigned short* __restrict__ W, const float* __restrict__ bias,
    float* __restrict__ C)
{
    __shared__ unsigned short As[128 * 64];
    __shared__ unsigned short Bs[64 * 64];
    const int tid = threadIdx.x, wave = tid >> 6, lane = tid & 63;
    const int mB = blockIdx.x * 128, nB = blockIdx.y * 64;
    const int lr = lane & 15, lq = lane >> 4;
    int aq[4], agr[4], apr[4];
    unsigned short* lA[4];
    const unsigned short* BgP[2];
    unsigned short* lB[2];
#pragma unroll
    for (int i = 0; i < 4; ++i) {
        int s = tid + i * 256;              // A: 1024 slots
        int r = s >> 3, p = s & 7;
        aq[i] = (p ^ (r & 7)) * 8;
        int gr = mB + r;
        agr[i] = gr;
        apr[i] = (gr & ~4095) | ((gr & 63) << 6) | ((gr >> 6) & 63);
        lA[i] = As + s * 8;
    }
#pragma unroll
    for (int i = 0; i < 2; ++i) {
        int s = tid + i * 256;              // B: 512 slots
        int r = s >> 3, p = s & 7;
        int q = p ^ (r & 7);
        BgP[i] = W + (size_t)(nB + r) * 2048 + q * 8;
        lB[i] = Bs + s * 8;
    }
    const int aswz = lr & 7;
    int arb[2], brb[4];
#pragma unroll
    for (int i = 0; i < 2; ++i) arb[i] = (wave * 32 + i * 16 + lr) * 64;
#pragma unroll
    for (int i = 0; i < 4; ++i) brb[i] = (i * 16 + lr) * 64;
    f32x4 zero4 = {0.f,0.f,0.f,0.f};
    f32x4 acc[2][4] = {{zero4,zero4,zero4,zero4},{zero4,zero4,zero4,zero4}};
    for (int k0 = 0; k0 < 2048; k0 += 64) {
#pragma unroll
        for (int i = 0; i < 4; ++i) {
            int kk = k0 + aq[i];
            const unsigned short* g = (kk < 1024)
                ? YV + (size_t)apr[i] * 1024 + kk
                : YH + (size_t)agr[i] * 1024 + (kk - 1024);
            async_lds16(g, lA[i]);
        }
#pragma unroll
        for (int i = 0; i < 2; ++i) async_lds16(BgP[i] + k0, lB[i]);
        __syncthreads();
#pragma unroll
        for (int kh = 0; kh < 2; ++kh) {
            const int ksw = ((kh * 4 + lq) ^ aswz) * 8;
            bf16x8 a[2], b[4];
#pragma unroll
            for (int i = 0; i < 2; ++i) a[i] = *(const bf16x8*)(As + arb[i] + ksw);
#pragma unroll
            for (int i = 0; i < 4; ++i) b[i] = *(const bf16x8*)(Bs + brb[i] + ksw);
#pragma unroll
            for (int mi = 0; mi < 2; ++mi)
#pragma unroll
                for (int ni = 0; ni < 4; ++ni)
                    acc[mi][ni] = __builtin_amdgcn_mfma_f32_16x16x32_bf16(
                        a[mi], b[ni], acc[mi][ni], 0, 0, 0);
        }
        __syncthreads();
    }
    const int rbase = lq * 4;
#pragma unroll
    for (int mi = 0; mi < 2; ++mi)
#pragma unroll
        for (int ni = 0; ni < 4; ++ni) {
            int col = nB + ni * 16 + lr;
            float bb = bias[col];
#pragma unroll
            for (int r = 0; r < 4; ++r) {
                int row = mB + wave * 32 + mi * 16 + rbase + r;
                C[(size_t)row * 512 + col] = acc[mi][ni][r] + bb;
            }
        }
}

// ---------------------------------------------------------------------------
// Causal depthwise conv (k=4) + bias + SiLU, dir-merged (grid.y = dir).
// ---------------------------------------------------------------------------
__global__ __launch_bounds__(320) void conv_silu(
    const unsigned short* __restrict__ zxb, const float* __restrict__ cw0,
    const float* __restrict__ cw1, const float* __restrict__ cb0,
    const float* __restrict__ cb1, unsigned short* __restrict__ xbcb)
{
    __shared__ unsigned short S[64 * 320];
    const int dir = blockIdx.y;
    const unsigned short* zx = zxb + (size_t)dir * NROWS * NZX;
    unsigned short* xbc = xbcb + (size_t)dir * NROWS * 1280;
    const float* cw = dir ? cw1 : cw0;
    const float* cb = dir ? cb1 : cb0;
    const int tid = threadIdx.x;
    const int seq = blockIdx.x >> 2, tile = blockIdx.x & 3;
    const int cbase = tile * 320;
    const unsigned short* src = zx + (size_t)seq * 64 * NZX + 1024 + cbase;
#pragma unroll
    for (int i = 0; i < 8; ++i) {
        int slot = tid + i * 320;
        int r = slot / 40, ch = (slot % 40) * 8;
        *(uint4*)(S + r * 320 + ch) = *(const uint4*)(src + (size_t)r * NZX + ch);
    }
    __syncthreads();
    const int c8 = (tid % 40) * 8, rg = tid / 40;
    const int gc = cbase + c8;
    float4 b0 = *(const float4*)(cb + gc), b1 = *(const float4*)(cb + gc + 4);
    const float bias[8] = {b0.x,b0.y,b0.z,b0.w,b1.x,b1.y,b1.z,b1.w};
    float4 wv[8];
#pragma unroll
    for (int j = 0; j < 8; ++j) wv[j] = *(const float4*)(cw + (size_t)(gc + j) * 4);
    unsigned short* dst = xbc + (size_t)seq * 64 * 1280 + gc;
#pragma unroll
    for (int r = 0; r < 8; ++r) {
        int t = rg * 8 + r;
        float acc[8];
#pragma unroll
        for (int j = 0; j < 8; ++j) acc[j] = bias[j];
#pragma unroll
        for (int k = 0; k < 4; ++k) {
            int ts = t + k - 3;
            if (ts >= 0) {
                uint4 xv = *(const uint4*)(S + ts * 320 + c8);
                const unsigned short* xs = (const unsigned short*)&xv;
#pragma unroll
                for (int j = 0; j < 8; ++j)
                    acc[j] += bf2f(xs[j]) * ((const float*)&wv[j])[k];
            }
        }
        unsigned short out8[8] __attribute__((aligned(16)));
#pragma unroll
        for (int j = 0; j < 8; ++j) out8[j] = f2bf(acc[j] / (1.f + __expf(-acc[j])));
        *(uint4*)(dst + (size_t)t * 1280) = *(const uint4*)out8;
    }
}

// ---------------------------------------------------------------------------
// Scan, 2 heads/block, dir-merged: grid (1024, 2). XCD swizzle: bid low 3
// bits = seq&7 so all 8 blocks of a seq share an XCD (B/C L2-resident).
// Phase1 G=C·B^T once per pair; per head: mask -> y=M·X + D*x -> coalesced out.
// ---------------------------------------------------------------------------
__global__ __launch_bounds__(256) void scan_kernel(
    const unsigned short* __restrict__ xbcb, const float* __restrict__ dtbb,
    const float* __restrict__ csbb, const float* __restrict__ Dv0,
    const float* __restrict__ Dv1, unsigned short* __restrict__ yh,
    unsigned short* __restrict__ yv)
{
    __shared__ unsigned short Bs[64 * BCS];
    __shared__ unsigned short Cs[64 * BCS];
    __shared__ unsigned short XsT[2][64 * XMS];
    __shared__ unsigned short Ms[64 * XMS];
    __shared__ float dts[2][64], css[2][64];
    const int dir = blockIdx.y;
    const unsigned short* xbc = xbcb + (size_t)dir * NROWS * 1280;
    const float* dtb = dtbb + (size_t)dir * 131072;
    const float* csb = csbb + (size_t)dir * 131072;
    const float* Dv = dir ? Dv1 : Dv0;
    unsigned short* y = dir ? yv : yh;
    const int tid = threadIdx.x;
    const int lane = tid & 63, wave = tid >> 6;
    const int bxr = blockIdx.x;
    const int seq = (bxr & 7) | ((bxr >> 6) << 3);
    const int hp = (bxr >> 3) & 7;          // head pair 0..7
    if (tid < 128) {
        int hh = tid >> 6, t = tid & 63;
        dts[hh][t] = dtb[(seq * 16 + hp * 2 + hh) * 64 + t];
        css[hh][t] = csb[(seq * 16 + hp * 2 + hh) * 64 + t];
    }
    const unsigned short* base = xbc + (size_t)seq * 64 * 1280;
#pragma unroll
    for (int i = 0; i < 4; ++i) {
        int e = (tid + i * 256) * 8;
        int r = e >> 7, c = e & 127;
        *(uint4*)(Bs + r * BCS + c) = *(const uint4*)(base + (size_t)r * 1280 + 1024 + c);
        *(uint4*)(Cs + r * BCS + c) = *(const uint4*)(base + (size_t)r * 1280 + 1152 + c);
    }
#pragma unroll
    for (int i = 0; i < 4; ++i) {
        int e = (tid + i * 256) * 8;        // 8192 elems: 64 t x 128 cols
        int t = e >> 7, c0 = e & 127;
        int hh = c0 >> 6, p0 = c0 & 63;
        uint4 xval = *(const uint4*)(base + (size_t)t * 1280 + hp * 128 + c0);
        const unsigned short* xsv = (const unsigned short*)&xval;
#pragma unroll
        for (int j = 0; j < 8; ++j) {
            int jl = (j + lane) & 7;
            XsT[hh][(p0 + jl) * XMS + t] = xsv[jl];
        }
    }
    __syncthreads();
    const int lr = lane & 15, lq = lane >> 4;
    f32x4 zero4 = {0.f,0.f,0.f,0.f};
    f32x4 acc[4] = {zero4, zero4, zero4, zero4};
#pragma unroll
    for (int kt = 0; kt < 4; ++kt) {
        bf16x8 a = *(const bf16x8*)(Cs + (wave * 16 + lr) * BCS + kt * 32 + lq * 8);
#pragma unroll
        for (int ni = 0; ni < 4; ++ni) {
            bf16x8 b = *(const bf16x8*)(Bs + (ni * 16 + lr) * BCS + kt * 32 + lq * 8);
            acc[ni] = __builtin_amdgcn_mfma_f32_16x16x32_bf16(a, b, acc[ni], 0, 0, 0);
        }
    }
    for (int hh = 0; hh < 2; ++hh) {
        float css_t[4];
#pragma unroll
        for (int r = 0; r < 4; ++r) css_t[r] = css[hh][wave * 16 + lq * 4 + r];
#pragma unroll
        for (int ni = 0; ni < 4; ++ni) {
            int s = ni * 16 + lr;
            float cs_s = css[hh][s], dt_s = dts[hh][s];
#pragma unroll
            for (int r = 0; r < 4; ++r) {
                int t = wave * 16 + lq * 4 + r;
                float e = __expf(fminf(css_t[r] - cs_s, 0.f));
                float m = (s <= t) ? acc[ni][r] * e * dt_s : 0.f;
                Ms[t * XMS + s] = f2bf(m);
            }
        }
        __syncthreads();
        f32x4 yacc[4] = {zero4, zero4, zero4, zero4};
#pragma unroll
        for (int kt = 0; kt < 2; ++kt) {
            bf16x8 a = *(const bf16x8*)(Ms + (wave * 16 + lr) * XMS + kt * 32 + lq * 8);
#pragma unroll
            for (int ni = 0; ni < 4; ++ni) {
                bf16x8 b = *(const bf16x8*)(XsT[hh] + (ni * 16 + lr) * XMS + kt * 32 + lq * 8);
                yacc[ni] = __builtin_amdgcn_mfma_f32_16x16x32_bf16(a, b, yacc[ni], 0, 0, 0);
            }
        }
        __syncthreads();   // all Ms reads done before restaging
        const float Dh = Dv[hp * 2 + hh];
#pragma unroll
        for (int ni = 0; ni < 4; ++ni) {
            int p = ni * 16 + lr;
#pragma unroll
            for (int r = 0; r < 4; ++r) {
                int t = wave * 16 + lq * 4 + r;
                float v = yacc[ni][r] + Dh * bf2f(XsT[hh][p * XMS + t]);
                Ms[t * XMS + p] = f2bf(v);
            }
        }
        __syncthreads();
        unsigned short* yout = y + (size_t)seq * 64 * 1024 + (hp * 2 + hh) * 64;
#pragma unroll
        for (int i = 0; i < 2; ++i) {
            int slot = tid + i * 256;      // 512 slots = 64 rows x 8 chunks
            int t = slot >> 3, pc = (slot & 7) * 8;
            uint4 v = *(const uint4*)(Ms + t * XMS + pc);
            *(uint4*)(yout + (size_t)t * 1024 + pc) = v;
        }
        __syncthreads();   // store reads done before next head's mask-write
    }
}

// ---------------------------------------------------------------------------
// Gate with silu(z) + RMSNorm, dir-merged: grid (8192, 2).
// ---------------------------------------------------------------------------
__global__ __launch_bounds__(128) void gate_norm(
    const unsigned short* __restrict__ zxb, unsigned short* __restrict__ yh,
    unsigned short* __restrict__ yv, const float* __restrict__ nw0,
    const float* __restrict__ nw1)
{
    const int dir = blockIdx.y;
    const unsigned short* zx = zxb + (size_t)dir * NROWS * NZX;
    unsigned short* y = dir ? yv : yh;
    const float* nw = dir ? nw1 : nw0;
    const int row = blockIdx.x, tid = threadIdx.x;
    uint4 yv4 = *(const uint4*)(y + (size_t)row * 1024 + tid * 8);
    uint4 zv4 = *(const uint4*)(zx + (size_t)row * NZX + tid * 8);
    const unsigned short* ys = (const unsigned short*)&yv4;
    const unsigned short* zs = (const unsigned short*)&zv4;
    float g[8]; float ss = 0.f;
#pragma unroll
    for (int j = 0; j < 8; ++j) {
        float zv = bf2f(zs[j]);
        float gv = bf2f(ys[j]) * (zv / (1.f + __expf(-zv)));
        g[j] = gv; ss += gv * gv;
    }
#pragma unroll
    for (int off = 32; off > 0; off >>= 1) ss += __shfl_xor(ss, off, 64);
    __shared__ float red[2];
    if ((tid & 63) == 0) red[tid >> 6] = ss;
    __syncthreads();
    ss = red[0] + red[1];
    const float scale = rsqrtf(ss * (1.f / 1024.f) + 1e-5f);
    unsigned short out8[8] __attribute__((aligned(16)));
#pragma unroll
    for (int j = 0; j < 8; ++j) out8[j] = f2bf(g[j] * scale * nw[tid * 8 + j]);
    *(uint4*)(y + (size_t)row * 1024 + tid * 8) = *(const uint4*)out8;
}

extern "C" void kernel_launch(void* const* d_in, const int* in_sizes, int n_in,
                              void* d_out, int out_size, void* d_ws, size_t ws_size,
                              hipStream_t stream)
{
    (void)in_sizes; (void)n_in; (void)out_size; (void)ws_size;
    const float* x   = (const float*)d_in[0];
    const float* fcw = (const float*)d_in[17];
    const float* fcb = (const float*)d_in[18];
    const float* iw0 = (const float*)d_in[1];  const float* iw1 = (const float*)d_in[9];
    const float* cw0 = (const float*)d_in[2];  const float* cw1 = (const float*)d_in[10];
    const float* cb0 = (const float*)d_in[3];  const float* cb1 = (const float*)d_in[11];
    const float* al0 = (const float*)d_in[4];  const float* al1 = (const float*)d_in[12];
    const float* db0 = (const float*)d_in[5];  const float* db1 = (const float*)d_in[13];
    const float* Dv0 = (const float*)d_in[6];  const float* Dv1 = (const float*)d_in[14];
    const float* nw0 = (const float*)d_in[7];  const float* nw1 = (const float*)d_in[15];
    const float* ow0 = (const float*)d_in[8];  const float* ow1 = (const float*)d_in[16];

    char* ws = (char*)d_ws;
    size_t off = 0;
    auto alloc = [&](size_t bytes) {
        void* p = ws + off; off += (bytes + 255) & ~(size_t)255; return p;
    };
    unsigned short* xbf   = (unsigned short*)alloc((size_t)NROWS * 512 * 2);
    unsigned short* wbA   = (unsigned short*)alloc((size_t)2 * 2304 * 512 * 2);
    unsigned short* wbOT0 = (unsigned short*)alloc((size_t)1024 * 512 * 2);
    unsigned short* wbOT1 = (unsigned short*)alloc((size_t)1024 * 512 * 2);
    unsigned short* wf    = (unsigned short*)alloc((size_t)512 * 1024 * 2);
    unsigned short* wcomb = (unsigned short*)alloc((size_t)512 * 2048 * 2);
    unsigned short* zx    = (unsigned short*)alloc((size_t)2 * NROWS * NZX * 2);
    unsigned short* xbc   = (unsigned short*)alloc((size_t)2 * NROWS * 1280 * 2);
    float* dtb            = (float*)alloc((size_t)2 * 2048 * 64 * 4);
    float* csb            = (float*)alloc((size_t)2 * 2048 * 64 * 4);
    unsigned short* ybh   = (unsigned short*)alloc((size_t)NROWS * 1024 * 2);
    unsigned short* ybv   = (unsigned short*)alloc((size_t)NROWS * 1024 * 2);

    prep_kernel<<<PB3, 256, 0, stream>>>(x, fcw, iw0, iw1, ow0, ow1, db0, db1,
                                         al0, al1, xbf, wf, wbA, wbOT0, wbOT1,
                                         dtb, csb);
    gemm_phase<<<dim3(68, 18, 2), 256, 0, stream>>>(xbf, wbA, zx, wf,
                                                    wbOT0, wbOT1, wcomb);
    conv_silu<<<dim3(512, 2), 320, 0, stream>>>(zx, cw0, cw1, cb0, cb1, xbc);
    scan_kernel<<<dim3(1024, 2), 256, 0, stream>>>(xbc, dtb, csb, Dv0, Dv1, ybh, ybv);
    gate_norm<<<dim3(NROWS, 2), 128, 0, stream>>>(zx, ybh, ybv, nw0, nw1);
    gemm_final2048<<<dim3(64, 8), 256, 0, stream>>>(ybv, ybh, wcomb, fcb, (float*)d_out);
}

// Round 12
// 289.853 us; speedup vs baseline: 1.0574x; 1.0574x over previous
//
#include <hip/hip_runtime.h>

#define NROWS 8192      // 128 sequences * 64 positions
#define NZX   2304      // z (1024) + xBC (1280) columns from in-proj
#define BCS   136       // Bs/Cs LDS row stride (elements, padded)
#define XMS   72        // XsT/Ms LDS row stride (elements, padded)

// prep kernel block ranges (R10 layout)
#define PB0 4096            // cvt x -> xbf
#define PB1 (PB0 + 2048)    // fold_w
#define PB2 (PB1 + 2304)    // cvt in_w (both dirs)
#define PB3 (PB2 + 256)     // cvtT out_w (both dirs)
#define PB4 (PB3 + 512)     // dt_cs (both dirs, 8 heads/block)

typedef __attribute__((ext_vector_type(8))) short bf16x8;
typedef __attribute__((ext_vector_type(4))) float f32x4;

__device__ __forceinline__ float bf2f(unsigned short u) {
    union { unsigned int i; float f; } v; v.i = ((unsigned int)u) << 16; return v.f;
}
// fast bf16 round (half-up): 2 VALU ops
__device__ __forceinline__ unsigned short f2bf(float f) {
    union { float f; unsigned int i; } v; v.f = f;
    return (unsigned short)((v.i + 0x8000u) >> 16);
}

// async global->LDS, 16B per lane; lane's LDS slot must be wave-base + lane*16.
__device__ __forceinline__ void async_lds16(const unsigned short* g, unsigned short* l) {
    __builtin_amdgcn_global_load_lds(
        (const __attribute__((address_space(1))) unsigned int*)g,
        (__attribute__((address_space(3))) unsigned int*)l, 16, 0, 0);
}

// ---------------------------------------------------------------------------
// PREP: all input conversions + dt/cumsum path, block-range dispatched. (R10)
// ---------------------------------------------------------------------------
__global__ __launch_bounds__(256) void prep_kernel(
    const float* __restrict__ x, const float* __restrict__ fcw,
    const float* __restrict__ iw0, const float* __restrict__ iw1,
    const float* __restrict__ ow0, const float* __restrict__ ow1,
    const float* __restrict__ db0, const float* __restrict__ db1,
    const float* __restrict__ al0, const float* __restrict__ al1,
    unsigned short* __restrict__ xbf, unsigned short* __restrict__ wf,
    unsigned short* __restrict__ wbA, unsigned short* __restrict__ wbOT0,
    unsigned short* __restrict__ wbOT1, float* __restrict__ dtbb,
    float* __restrict__ csbb)
{
    __shared__ char sm[37888] __attribute__((aligned(16)));
    const int blk = blockIdx.x, tid = threadIdx.x;
    if (blk < PB0) {
        int i = blk * 256 + tid;
        float4 v = *(const float4*)(x + (size_t)i * 4);
        ushort4 o;
        o.x = f2bf(v.x); o.y = f2bf(v.y); o.z = f2bf(v.z); o.w = f2bf(v.w);
        *(ushort4*)(xbf + (size_t)i * 4) = o;
    } else if (blk < PB1) {
        int idx = (blk - PB0) * 256 + tid;
        int o = idx >> 10, c = idx & 1023;
        int half = c >> 9, cc = c & 511;
        float v = fcw[(size_t)o * 2048 + half * 1024 + cc] +
                  fcw[(size_t)o * 2048 + half * 1024 + 512 + cc];
        wf[idx] = f2bf(v);
    } else if (blk < PB2) {
        int local = blk - PB1;
        int dir = local / 1152;
        int i = (local % 1152) * 256 + tid;
        const float* s = dir ? iw1 : iw0;
        float4 v = *(const float4*)(s + (size_t)i * 4);
        ushort4 o;
        o.x = f2bf(v.x); o.y = f2bf(v.y); o.z = f2bf(v.z); o.w = f2bf(v.w);
        *(ushort4*)(wbA + (size_t)dir * (2304 * 512) + (size_t)i * 4) = o;
    } else if (blk < PB3) {
        float (*T)[65] = (float(*)[65])sm;
        int local = blk - PB2;
        int z = local >> 7, rem = local & 127;
        const float* s = z ? ow1 : ow0;
        unsigned short* d = z ? wbOT1 : wbOT0;
        const int bo = (rem >> 4) * 64, bc = (rem & 15) * 64;
#pragma unroll
        for (int i = 0; i < 16; ++i) {
            int slot = tid + i * 256;
            int r = slot >> 6, c = slot & 63;
            T[r][c] = s[(size_t)(bo + r) * 1024 + bc + c];
        }
        __syncthreads();
#pragma unroll
        for (int i = 0; i < 16; ++i) {
            int slot = tid + i * 256;
            int cr = slot >> 6, oc = slot & 63;
            d[(size_t)(bc + cr) * 512 + bo + oc] = f2bf(T[oc][cr]);
        }
    } else {
        // dt path fp32, both dirs; 256 blocks per dir; block = (seq, 8-head half)
        float (*wsm)[512] = (float(*)[512])sm;                       // 16 KB
        float (*xs)[68]   = (float(*)[68])(sm + 16384);              // 17.4 KB
        float (*dta)[64]  = (float(*)[64])(sm + 16384 + 17408);      // 2 KB
        float (*dtt)[64]  = (float(*)[64])(sm + 16384 + 17408 + 2048);
        int local = blk - PB3;
        const int dir = local >> 8, bxl = local & 255;
        const float* in_w = dir ? iw1 : iw0;
        const float* dt_bias = dir ? db1 : db0;
        const float* A_log = dir ? al1 : al0;
        float* dtb = dtbb + (size_t)dir * 131072;
        float* csb = csbb + (size_t)dir * 131072;
        const int seq = bxl >> 1, hq = bxl & 1;
#pragma unroll
        for (int i = 0; i < 4; ++i) {
            int slot = tid + i * 256;
            int h = slot >> 7, c = (slot & 127) * 4;
            *(float4*)&wsm[h][c] = *(const float4*)(in_w + (size_t)(2304 + hq * 8 + h) * 512 + c);
        }
        const int t = tid & 63, hg = tid >> 6;   // 2 heads per thread
        float acc[2] = {0.f, 0.f};
        for (int c0 = 0; c0 < 512; c0 += 64) {
            __syncthreads();
#pragma unroll
            for (int i = 0; i < 4; ++i) {
                int slot = tid + i * 256;
                int r = slot >> 4, cc = (slot & 15) * 4;
                size_t row = (dir == 0) ? (size_t)seq * 64 + r
                                        : (size_t)(seq >> 6) * 4096 + (size_t)r * 64 + (seq & 63);
                *(float4*)&xs[r][cc] = *(const float4*)(x + row * 512 + c0 + cc);
            }
            __syncthreads();
#pragma unroll
            for (int cc = 0; cc < 64; cc += 4) {
                float4 u4 = *(const float4*)&xs[t][cc];
                const float* w0 = &wsm[hg * 2][c0 + cc];
                const float* w1 = &wsm[hg * 2 + 1][c0 + cc];
                acc[0] += u4.x * w0[0] + u4.y * w0[1] + u4.z * w0[2] + u4.w * w0[3];
                acc[1] += u4.x * w1[0] + u4.y * w1[1] + u4.z * w1[2] + u4.w * w1[3];
            }
        }
#pragma unroll
        for (int hh = 0; hh < 2; ++hh) {
            int hl = hg * 2 + hh;
            int h = hq * 8 + hl;
            float v = acc[hh] + dt_bias[h];
            float dtv = (v > 20.f) ? v : log1pf(__expf(v));
            dtt[hl][t] = dtv;
            dta[hl][t] = dtv * -__expf(A_log[h]);
        }
        __syncthreads();
        if (tid < 8) {
            float run = 0.f;
            int ob = (seq * 16 + hq * 8 + tid) * 64;
            for (int tt = 0; tt < 64; ++tt) {
                run += dta[tid][tt];
                dtb[ob + tt] = dtt[tid][tt];
                csb[ob + tt] = run;
            }
        }
    }
}

// ---------------------------------------------------------------------------
// GEMM phase (one launch, BK=64): bx<64 -> in-proj (M=8192,N=2304,K=512,
// perm on z=1); bx>=64 -> wcomb halves (M=512,N=1024,K=512). bf16 out. (R10)
// ---------------------------------------------------------------------------
__global__ __launch_bounds__(256) void gemm_phase(
    const unsigned short* __restrict__ xbf, const unsigned short* __restrict__ wbA,
    unsigned short* __restrict__ zx, const unsigned short* __restrict__ wf,
    const unsigned short* __restrict__ wbOT0, const unsigned short* __restrict__ wbOT1,
    unsigned short* __restrict__ wcomb)
{
    __shared__ unsigned short SMEM[16384];   // As = [0,8192), Bs = [8192,16384)
    unsigned short* As = SMEM;
    unsigned short* Bs = SMEM + 8192;
    const int bx = blockIdx.x, by = blockIdx.y, z = blockIdx.z;
    const unsigned short *A, *B;
    unsigned short* C;
    int lda, ldb, ldc, perm, mB, nB;
    if (bx < 64) {
        A = xbf; lda = 512; perm = z;
        B = wbA + (size_t)z * (2304 * 512); ldb = 512;
        C = zx + (size_t)z * NROWS * NZX; ldc = NZX;
        mB = bx * 128; nB = by * 128;
    } else {
        if (by >= 8) return;
        A = z ? wf : wf + 512; lda = 1024; perm = 0;
        B = z ? wbOT1 : wbOT0; ldb = 512;
        C = z ? wcomb : wcomb + 1024; ldc = 2048;
        mB = (bx - 64) * 128; nB = by * 128;
    }
    const int tid = threadIdx.x, wave = tid >> 6, lane = tid & 63;
    const int wm = (wave >> 1) * 64, wn = (wave & 1) * 64;
    const int lr = lane & 15, lq = lane >> 4;
    const unsigned short* AgP[4];
    const unsigned short* BgP[4];
    unsigned short* lA[4];
    unsigned short* lB[4];
#pragma unroll
    for (int i = 0; i < 4; ++i) {
        int s = tid + i * 256;              // 1024 slots each
        int r = s >> 3, p = s & 7;
        int q = p ^ (r & 7);
        int ar = mB + r;
        if (perm) ar = (ar & ~4095) | ((ar & 63) << 6) | ((ar >> 6) & 63);
        AgP[i] = A + (size_t)ar * lda + q * 8;
        BgP[i] = B + (size_t)(nB + r) * ldb + q * 8;
        lA[i] = As + s * 8;
        lB[i] = Bs + s * 8;
    }
    const int aswz = lr & 7;
    int arb[4], brb[4];
#pragma unroll
    for (int i = 0; i < 4; ++i) {
        arb[i] = (wm + i * 16 + lr) * 64;
        brb[i] = (wn + i * 16 + lr) * 64;
    }
    f32x4 zero4 = {0.f,0.f,0.f,0.f};
    f32x4 acc[4][4] = {{zero4,zero4,zero4,zero4},{zero4,zero4,zero4,zero4},
                       {zero4,zero4,zero4,zero4},{zero4,zero4,zero4,zero4}};
    for (int k0 = 0; k0 < 512; k0 += 64) {
#pragma unroll
        for (int i = 0; i < 4; ++i) async_lds16(AgP[i] + k0, lA[i]);
#pragma unroll
        for (int i = 0; i < 4; ++i) async_lds16(BgP[i] + k0, lB[i]);
        __syncthreads();
#pragma unroll
        for (int kh = 0; kh < 2; ++kh) {
            const int ksw = ((kh * 4 + lq) ^ aswz) * 8;
            bf16x8 a[4], b[4];
#pragma unroll
            for (int i = 0; i < 4; ++i) a[i] = *(const bf16x8*)(As + arb[i] + ksw);
#pragma unroll
            for (int i = 0; i < 4; ++i) b[i] = *(const bf16x8*)(Bs + brb[i] + ksw);
#pragma unroll
            for (int mi = 0; mi < 4; ++mi)
#pragma unroll
                for (int ni = 0; ni < 4; ++ni)
                    acc[mi][ni] = __builtin_amdgcn_mfma_f32_16x16x32_bf16(
                        a[mi], b[ni], acc[mi][ni], 0, 0, 0);
        }
        __syncthreads();
    }
    // ---- epilogue: wave-private 16x64 LDS tile, granule-rotated, 16B stores
    unsigned short* WR = SMEM + wave * 1024;
#pragma unroll
    for (int mi = 0; mi < 4; ++mi) {
#pragma unroll
        for (int ni = 0; ni < 4; ++ni) {
#pragma unroll
            for (int r = 0; r < 4; ++r) {
                int r16 = lq * 4 + r;
                int cn = ni * 16 + lr;
                int gp = ((cn >> 3) + (r16 >> 1)) & 7;
                WR[r16 * 64 + gp * 8 + (cn & 7)] = f2bf(acc[mi][ni][r]);
            }
        }
#pragma unroll
        for (int j = 0; j < 2; ++j) {
            int r16 = j * 8 + (lane >> 3);
            int gr = lane & 7;
            int gp = (gr + (r16 >> 1)) & 7;
            uint4 v = *(const uint4*)(WR + r16 * 64 + gp * 8);
            int row = mB + wm + mi * 16 + r16;
            *(uint4*)(C + (size_t)row * ldc + nB + wn + gr * 8) = v;
        }
    }
}

// ---------------------------------------------------------------------------
// Final GEMM, 128x64 tiles, BK=64 (512 blocks). (R10)
// ---------------------------------------------------------------------------
__global__ __launch_bounds__(256) void gemm_final2048(
    const unsigned short* __restrict__ YV, const unsigned short* __restrict__ YH,
    const unsigned short* __restrict__ W, const float* __restrict__ bias,
    float* __restrict__ C)
{
    __shared__ unsigned short As[128 * 64];
    __shared__ unsigned short Bs[64 * 64];
    const int tid = threadIdx.x, wave = tid >> 6, lane = tid & 63;
    const int mB = blockIdx.x * 128, nB = blockIdx.y * 64;
    const int lr = lane & 15, lq = lane >> 4;
    int aq[4], agr[4], apr[4];
    unsigned short* lA[4];
    const unsigned short* BgP[2];
    unsigned short* lB[2];
#pragma unroll
    for (int i = 0; i < 4; ++i) {
        int s = tid + i * 256;              // A: 1024 slots
        int r = s >> 3, p = s & 7;
        aq[i] = (p ^ (r & 7)) * 8;
        int gr = mB + r;
        agr[i] = gr;
        apr[i] = (gr & ~4095) | ((gr & 63) << 6) | ((gr >> 6) & 63);
        lA[i] = As + s * 8;
    }
#pragma unroll
    for (int i = 0; i < 2; ++i) {
        int s = tid + i * 256;              // B: 512 slots
        int r = s >> 3, p = s & 7;
        int q = p ^ (r & 7);
        BgP[i] = W + (size_t)(nB + r) * 2048 + q * 8;
        lB[i] = Bs + s * 8;
    }
    const int aswz = lr & 7;
    int arb[2], brb[4];
#pragma unroll
    for (int i = 0; i < 2; ++i) arb[i] = (wave * 32 + i * 16 + lr) * 64;
#pragma unroll
    for (int i = 0; i < 4; ++i) brb[i] = (i * 16 + lr) * 64;
    f32x4 zero4 = {0.f,0.f,0.f,0.f};
    f32x4 acc[2][4] = {{zero4,zero4,zero4,zero4},{zero4,zero4,zero4,zero4}};
    for (int k0 = 0; k0 < 2048; k0 += 64) {
#pragma unroll
        for (int i = 0; i < 4; ++i) {
            int kk = k0 + aq[i];
            const unsigned short* g = (kk < 1024)
                ? YV + (size_t)apr[i] * 1024 + kk
                : YH + (size_t)agr[i] * 1024 + (kk - 1024);
            async_lds16(g, lA[i]);
        }
#pragma unroll
        for (int i = 0; i < 2; ++i) async_lds16(BgP[i] + k0, lB[i]);
        __syncthreads();
#pragma unroll
        for (int kh = 0; kh < 2; ++kh) {
            const int ksw = ((kh * 4 + lq) ^ aswz) * 8;
            bf16x8 a[2], b[4];
#pragma unroll
            for (int i = 0; i < 2; ++i) a[i] = *(const bf16x8*)(As + arb[i] + ksw);
#pragma unroll
            for (int i = 0; i < 4; ++i) b[i] = *(const bf16x8*)(Bs + brb[i] + ksw);
#pragma unroll
            for (int mi = 0; mi < 2; ++mi)
#pragma unroll
                for (int ni = 0; ni < 4; ++ni)
                    acc[mi][ni] = __builtin_amdgcn_mfma_f32_16x16x32_bf16(
                        a[mi], b[ni], acc[mi][ni], 0, 0, 0);
        }
        __syncthreads();
    }
    const int rbase = lq * 4;
#pragma unroll
    for (int mi = 0; mi < 2; ++mi)
#pragma unroll
        for (int ni = 0; ni < 4; ++ni) {
            int col = nB + ni * 16 + lr;
            float bb = bias[col];
#pragma unroll
            for (int r = 0; r < 4; ++r) {
                int row = mB + wave * 32 + mi * 16 + rbase + r;
                C[(size_t)row * 512 + col] = acc[mi][ni][r] + bb;
            }
        }
}

// ---------------------------------------------------------------------------
// Causal depthwise conv (k=4) + bias + SiLU, dir-merged (grid.y = dir). (R10)
// ---------------------------------------------------------------------------
__global__ __launch_bounds__(320) void conv_silu(
    const unsigned short* __restrict__ zxb, const float* __restrict__ cw0,
    const float* __restrict__ cw1, const float* __restrict__ cb0,
    const float* __restrict__ cb1, unsigned short* __restrict__ xbcb)
{
    __shared__ unsigned short S[64 * 320];
    const int dir = blockIdx.y;
    const unsigned short* zx = zxb + (size_t)dir * NROWS * NZX;
    unsigned short* xbc = xbcb + (size_t)dir * NROWS * 1280;
    const float* cw = dir ? cw1 : cw0;
    const float* cb = dir ? cb1 : cb0;
    const int tid = threadIdx.x;
    const int seq = blockIdx.x >> 2, tile = blockIdx.x & 3;
    const int cbase = tile * 320;
    const unsigned short* src = zx + (size_t)seq * 64 * NZX + 1024 + cbase;
#pragma unroll
    for (int i = 0; i < 8; ++i) {
        int slot = tid + i * 320;
        int r = slot / 40, ch = (slot % 40) * 8;
        *(uint4*)(S + r * 320 + ch) = *(const uint4*)(src + (size_t)r * NZX + ch);
    }
    __syncthreads();
    const int c8 = (tid % 40) * 8, rg = tid / 40;
    const int gc = cbase + c8;
    float4 b0 = *(const float4*)(cb + gc), b1 = *(const float4*)(cb + gc + 4);
    const float bias[8] = {b0.x,b0.y,b0.z,b0.w,b1.x,b1.y,b1.z,b1.w};
    float4 wv[8];
#pragma unroll
    for (int j = 0; j < 8; ++j) wv[j] = *(const float4*)(cw + (size_t)(gc + j) * 4);
    unsigned short* dst = xbc + (size_t)seq * 64 * 1280 + gc;
#pragma unroll
    for (int r = 0; r < 8; ++r) {
        int t = rg * 8 + r;
        float acc[8];
#pragma unroll
        for (int j = 0; j < 8; ++j) acc[j] = bias[j];
#pragma unroll
        for (int k = 0; k < 4; ++k) {
            int ts = t + k - 3;
            if (ts >= 0) {
                uint4 xv = *(const uint4*)(S + ts * 320 + c8);
                const unsigned short* xs = (const unsigned short*)&xv;
#pragma unroll
                for (int j = 0; j < 8; ++j)
                    acc[j] += bf2f(xs[j]) * ((const float*)&wv[j])[k];
            }
        }
        unsigned short out8[8] __attribute__((aligned(16)));
#pragma unroll
        for (int j = 0; j < 8; ++j) out8[j] = f2bf(acc[j] / (1.f + __expf(-acc[j])));
        *(uint4*)(dst + (size_t)t * 1280) = *(const uint4*)out8;
    }
}

// ---------------------------------------------------------------------------
// G kernel: per (seq, dir) compute G = Cm·Bm^T (64x64, K=128) once, store
// fp32 to Gbuf[(dir*128+seq)*4096 + t*64 + s]. Grid (128, 2), 256 threads.
// ---------------------------------------------------------------------------
__global__ __launch_bounds__(256) void gmat_kernel(
    const unsigned short* __restrict__ xbcb, float* __restrict__ Gbuf)
{
    __shared__ unsigned short Bs[64 * BCS];
    __shared__ unsigned short Cs[64 * BCS];
    const int dir = blockIdx.y, seq = blockIdx.x;
    const unsigned short* base = xbcb + (size_t)dir * NROWS * 1280
                                      + (size_t)seq * 64 * 1280;
    const int tid = threadIdx.x;
    const int lane = tid & 63, wave = tid >> 6;
#pragma unroll
    for (int i = 0; i < 4; ++i) {
        int e = (tid + i * 256) * 8;
        int r = e >> 7, c = e & 127;
        *(uint4*)(Bs + r * BCS + c) = *(const uint4*)(base + (size_t)r * 1280 + 1024 + c);
        *(uint4*)(Cs + r * BCS + c) = *(const uint4*)(base + (size_t)r * 1280 + 1152 + c);
    }
    __syncthreads();
    const int lr = lane & 15, lq = lane >> 4;
    f32x4 zero4 = {0.f,0.f,0.f,0.f};
    f32x4 acc[4] = {zero4, zero4, zero4, zero4};
#pragma unroll
    for (int kt = 0; kt < 4; ++kt) {
        bf16x8 a = *(const bf16x8*)(Cs + (wave * 16 + lr) * BCS + kt * 32 + lq * 8);
#pragma unroll
        for (int ni = 0; ni < 4; ++ni) {
            bf16x8 b = *(const bf16x8*)(Bs + (ni * 16 + lr) * BCS + kt * 32 + lq * 8);
            acc[ni] = __builtin_amdgcn_mfma_f32_16x16x32_bf16(a, b, acc[ni], 0, 0, 0);
        }
    }
    float* G = Gbuf + ((size_t)dir * 128 + seq) * 4096;
#pragma unroll
    for (int ni = 0; ni < 4; ++ni) {
        int s = ni * 16 + lr;
#pragma unroll
        for (int r = 0; r < 4; ++r) {
            int t = wave * 16 + lq * 4 + r;
            G[t * 64 + s] = acc[ni][r];
        }
    }
}

// ---------------------------------------------------------------------------
// Scan (slim): per (seq, head), G loaded fp32 from Gbuf (same reg pattern as
// phase-1 output -> bit-identical). Mask -> Ms -> y = Ms·X + D*x. LDS ~19 KB.
// ---------------------------------------------------------------------------
__global__ __launch_bounds__(256) void scan_kernel(
    const unsigned short* __restrict__ xbcb, const float* __restrict__ Gbuf,
    const float* __restrict__ dtbb, const float* __restrict__ csbb,
    const float* __restrict__ Dv0, const float* __restrict__ Dv1,
    unsigned short* __restrict__ yh, unsigned short* __restrict__ yv)
{
    __shared__ unsigned short XsT[64 * XMS];
    __shared__ unsigned short Ms[64 * XMS];
    __shared__ float dts[64], css[64];
    const int dir = blockIdx.y;
    const unsigned short* xbc = xbcb + (size_t)dir * NROWS * 1280;
    const float* dtb = dtbb + (size_t)dir * 131072;
    const float* csb = csbb + (size_t)dir * 131072;
    const float* Dv = dir ? Dv1 : Dv0;
    unsigned short* y = dir ? yv : yh;
    const int tid = threadIdx.x;
    const int lane = tid & 63, wave = tid >> 6;
    const int seq = blockIdx.x >> 4, h = blockIdx.x & 15;
    if (tid < 64) {
        dts[tid] = dtb[(seq * 16 + h) * 64 + tid];
        css[tid] = csb[(seq * 16 + h) * 64 + tid];
    }
    const unsigned short* base = xbc + (size_t)seq * 64 * 1280;
#pragma unroll
    for (int i = 0; i < 2; ++i) {
        int e = (tid + i * 256) * 8;
        int t = e >> 6, p0 = e & 63;
        uint4 xval = *(const uint4*)(base + (size_t)t * 1280 + h * 64 + p0);
        const unsigned short* xs = (const unsigned short*)&xval;
#pragma unroll
        for (int j = 0; j < 8; ++j) {
            int jl = (j + lane) & 7;
            XsT[(p0 + jl) * XMS + t] = xs[jl];
        }
    }
    const int lr = lane & 15, lq = lane >> 4;
    // load G in the phase-1 output pattern (bit-identical to computing it)
    const float* G = Gbuf + ((size_t)dir * 128 + seq) * 4096;
    f32x4 acc[4];
#pragma unroll
    for (int ni = 0; ni < 4; ++ni) {
        int s = ni * 16 + lr;
#pragma unroll
        for (int r = 0; r < 4; ++r) {
            int t = wave * 16 + lq * 4 + r;
            acc[ni][r] = G[t * 64 + s];
        }
    }
    __syncthreads();
    float css_t[4];
#pragma unroll
    for (int r = 0; r < 4; ++r) css_t[r] = css[wave * 16 + lq * 4 + r];
#pragma unroll
    for (int ni = 0; ni < 4; ++ni) {
        int s = ni * 16 + lr;
        float cs_s = css[s], dt_s = dts[s];
#pragma unroll
        for (int r = 0; r < 4; ++r) {
            int t = wave * 16 + lq * 4 + r;
            float e = __expf(fminf(css_t[r] - cs_s, 0.f));
            float m = (s <= t) ? acc[ni][r] * e * dt_s : 0.f;
            Ms[t * XMS + s] = f2bf(m);
        }
    }
    __syncthreads();
    f32x4 zero4 = {0.f,0.f,0.f,0.f};
    f32x4 yacc[4] = {zero4, zero4, zero4, zero4};
#pragma unroll
    for (int kt = 0; kt < 2; ++kt) {
        bf16x8 a = *(const bf16x8*)(Ms + (wave * 16 + lr) * XMS + kt * 32 + lq * 8);
#pragma unroll
        for (int ni = 0; ni < 4; ++ni) {
            bf16x8 b = *(const bf16x8*)(XsT + (ni * 16 + lr) * XMS + kt * 32 + lq * 8);
            yacc[ni] = __builtin_amdgcn_mfma_f32_16x16x32_bf16(a, b, yacc[ni], 0, 0, 0);
        }
    }
    const float Dh = Dv[h];
    // stage y[t][p] into Ms rows (own wave band), then coalesced stores
#pragma unroll
    for (int ni = 0; ni < 4; ++ni) {
        int p = ni * 16 + lr;
#pragma unroll
        for (int r = 0; r < 4; ++r) {
            int t = wave * 16 + lq * 4 + r;
            float v = yacc[ni][r] + Dh * bf2f(XsT[p * XMS + t]);
            Ms[t * XMS + p] = f2bf(v);
        }
    }
    __syncthreads();
    unsigned short* yout = y + (size_t)seq * 64 * 1024 + h * 64;
#pragma unroll
    for (int i = 0; i < 2; ++i) {
        int slot = tid + i * 256;      // 512 slots = 64 rows x 8 chunks
        int t = slot >> 3, pc = (slot & 7) * 8;
        uint4 v = *(const uint4*)(Ms + t * XMS + pc);
        *(uint4*)(yout + (size_t)t * 1024 + pc) = v;
    }
}

// ---------------------------------------------------------------------------
// Gate with silu(z) + RMSNorm, dir-merged: grid (8192, 2). (R10)
// ---------------------------------------------------------------------------
__global__ __launch_bounds__(128) void gate_norm(
    const unsigned short* __restrict__ zxb, unsigned short* __restrict__ yh,
    unsigned short* __restrict__ yv, const float* __restrict__ nw0,
    const float* __restrict__ nw1)
{
    const int dir = blockIdx.y;
    const unsigned short* zx = zxb + (size_t)dir * NROWS * NZX;
    unsigned short* y = dir ? yv : yh;
    const float* nw = dir ? nw1 : nw0;
    const int row = blockIdx.x, tid = threadIdx.x;
    uint4 yv4 = *(const uint4*)(y + (size_t)row * 1024 + tid * 8);
    uint4 zv4 = *(const uint4*)(zx + (size_t)row * NZX + tid * 8);
    const unsigned short* ys = (const unsigned short*)&yv4;
    const unsigned short* zs = (const unsigned short*)&zv4;
    float g[8]; float ss = 0.f;
#pragma unroll
    for (int j = 0; j < 8; ++j) {
        float zv = bf2f(zs[j]);
        float gv = bf2f(ys[j]) * (zv / (1.f + __expf(-zv)));
        g[j] = gv; ss += gv * gv;
    }
#pragma unroll
    for (int off = 32; off > 0; off >>= 1) ss += __shfl_xor(ss, off, 64);
    __shared__ float red[2];
    if ((tid & 63) == 0) red[tid >> 6] = ss;
    __syncthreads();
    ss = red[0] + red[1];
    const float scale = rsqrtf(ss * (1.f / 1024.f) + 1e-5f);
    unsigned short out8[8] __attribute__((aligned(16)));
#pragma unroll
    for (int j = 0; j < 8; ++j) out8[j] = f2bf(g[j] * scale * nw[tid * 8 + j]);
    *(uint4*)(y + (size_t)row * 1024 + tid * 8) = *(const uint4*)out8;
}

extern "C" void kernel_launch(void* const* d_in, const int* in_sizes, int n_in,
                              void* d_out, int out_size, void* d_ws, size_t ws_size,
                              hipStream_t stream)
{
    (void)in_sizes; (void)n_in; (void)out_size; (void)ws_size;
    const float* x   = (const float*)d_in[0];
    const float* fcw = (const float*)d_in[17];
    const float* fcb = (const float*)d_in[18];
    const float* iw0 = (const float*)d_in[1];  const float* iw1 = (const float*)d_in[9];
    const float* cw0 = (const float*)d_in[2];  const float* cw1 = (const float*)d_in[10];
    const float* cb0 = (const float*)d_in[3];  const float* cb1 = (const float*)d_in[11];
    const float* al0 = (const float*)d_in[4];  const float* al1 = (const float*)d_in[12];
    const float* db0 = (const float*)d_in[5];  const float* db1 = (const float*)d_in[13];
    const float* Dv0 = (const float*)d_in[6];  const float* Dv1 = (const float*)d_in[14];
    const float* nw0 = (const float*)d_in[7];  const float* nw1 = (const float*)d_in[15];
    const float* ow0 = (const float*)d_in[8];  const float* ow1 = (const float*)d_in[16];

    char* ws = (char*)d_ws;
    size_t off = 0;
    auto alloc = [&](size_t bytes) {
        void* p = ws + off; off += (bytes + 255) & ~(size_t)255; return p;
    };
    unsigned short* xbf   = (unsigned short*)alloc((size_t)NROWS * 512 * 2);
    unsigned short* wbA   = (unsigned short*)alloc((size_t)2 * 2304 * 512 * 2);
    unsigned short* wbOT0 = (unsigned short*)alloc((size_t)1024 * 512 * 2);
    unsigned short* wbOT1 = (unsigned short*)alloc((size_t)1024 * 512 * 2);
    unsigned short* wf    = (unsigned short*)alloc((size_t)512 * 1024 * 2);
    unsigned short* wcomb = (unsigned short*)alloc((size_t)512 * 2048 * 2);
    unsigned short* zx    = (unsigned short*)alloc((size_t)2 * NROWS * NZX * 2);
    unsigned short* xbc   = (unsigned short*)alloc((size_t)2 * NROWS * 1280 * 2);
    float* Gbuf           = (float*)alloc((size_t)2 * 128 * 4096 * 4);
    float* dtb            = (float*)alloc((size_t)2 * 2048 * 64 * 4);
    float* csb            = (float*)alloc((size_t)2 * 2048 * 64 * 4);
    unsigned short* ybh   = (unsigned short*)alloc((size_t)NROWS * 1024 * 2);
    unsigned short* ybv   = (unsigned short*)alloc((size_t)NROWS * 1024 * 2);

    prep_kernel<<<PB4, 256, 0, stream>>>(x, fcw, iw0, iw1, ow0, ow1, db0, db1,
                                         al0, al1, xbf, wf, wbA, wbOT0, wbOT1,
                                         dtb, csb);
    gemm_phase<<<dim3(68, 18, 2), 256, 0, stream>>>(xbf, wbA, zx, wf,
                                                    wbOT0, wbOT1, wcomb);
    conv_silu<<<dim3(512, 2), 320, 0, stream>>>(zx, cw0, cw1, cb0, cb1, xbc);
    gmat_kernel<<<dim3(128, 2), 256, 0, stream>>>(xbc, Gbuf);
    scan_kernel<<<dim3(2048, 2), 256, 0, stream>>>(xbc, Gbuf, dtb, csb,
                                                   Dv0, Dv1, ybh, ybv);
    gate_norm<<<dim3(NROWS, 2), 128, 0, stream>>>(zx, ybh, ybv, nw0, nw1);
    gemm_final2048<<<dim3(64, 8), 256, 0, stream>>>(ybv, ybh, wcomb, fcb, (float*)d_out);
}